// Round 6
// baseline (148.524 us; speedup 1.0000x reference)
//
#include <hip/hip_runtime.h>

#define NB  32
#define NBH 16   // batches per half (ctxT buffer holds one half)
#define IDF 768
#define SLN 128
#define QLN 1024
#define NT  24   // IDF/32 k-tiles

typedef __bf16 v8bf __attribute__((ext_vector_type(8)));
typedef __bf16 v4bf __attribute__((ext_vector_type(4)));
typedef float  v4f  __attribute__((ext_vector_type(4)));

#define MFMA16 __builtin_amdgcn_mfma_f32_16x16x32_bf16

__device__ __forceinline__ void split2(float x, __bf16& h, __bf16& l) {
  h = (__bf16)x;
  l = (__bf16)(x - (float)h);
}

// -----------------------------------------------------------------------------
// K0: W [768*768] f32 -> Wh, Wl bf16 (same layout).
// -----------------------------------------------------------------------------
__global__ __launch_bounds__(256) void prep_w(const float* __restrict__ W,
                                              __bf16* __restrict__ Wh,
                                              __bf16* __restrict__ Wl) {
  int idx = blockIdx.x * 1024 + threadIdx.x * 4;
  float4 v = *(const float4*)(W + idx);
  float vals[4] = {v.x, v.y, v.z, v.w};
  v4bf h, l;
#pragma unroll
  for (int e = 0; e < 4; ++e) {
    __bf16 hh, ll;
    split2(vals[e], hh, ll);
    h[e] = hh;
    l[e] = ll;
  }
  *(v4bf*)(Wh + idx) = h;
  *(v4bf*)(Wl + idx) = l;
}

// -----------------------------------------------------------------------------
// K0b: ctx [b][c][s] f32 -> ctxT hi/lo [bb][s][c] bf16 for one 16-batch half.
// Grid (12 c-tiles of 64, 16 b). LDS transpose, split once.
// -----------------------------------------------------------------------------
__global__ __launch_bounds__(256) void prep_ctx(const float* __restrict__ ctx,
                                                __bf16* __restrict__ cTh,
                                                __bf16* __restrict__ cTl,
                                                int bh) {
  const int bb = blockIdx.y, b = bh * NBH + bb;
  const int c0 = blockIdx.x * 64;
  const int t = threadIdx.x;
  __shared__ float tl[64][133];
#pragma unroll
  for (int j = 0; j < 8; ++j) {  // load 64c x 128s, coalesced
    int u = j * 256 + t;
    int c = u >> 5, s4 = (u & 31) * 4;
    *(float4*)&tl[c][s4] =
        *(const float4*)(ctx + ((size_t)b * IDF + c0 + c) * SLN + s4);
  }
  __syncthreads();
#pragma unroll
  for (int j = 0; j < 8; ++j) {  // write [s][c], split
    int u = j * 256 + t;
    int s = u >> 4, c4 = (u & 15) * 4;
    v4bf h, l;
#pragma unroll
    for (int e = 0; e < 4; ++e) {
      __bf16 hh, ll;
      split2(tl[c4 + e][s], hh, ll);
      h[e] = hh;
      l[e] = ll;
    }
    *(v4bf*)(cTh + ((size_t)bb * SLN + s) * IDF + c0 + c4) = h;
    *(v4bf*)(cTl + ((size_t)bb * SLN + s) * IDF + c0 + c4) = l;
  }
}

// -----------------------------------------------------------------------------
// K1 proj: D[s][o] = sum_c ctxT[s][c] * W[o][c].  Tile 128s x 32o, grid
// (24, 16) per half. Wave layout: ws = w>>1 (s-half 64), wq = w&1 (o-16).
// A = ctxT hi/lo staged via chunk-XOR-swizzled LDS (qk-verified scheme),
// B = Wh/Wl frags reg-prefetched from global (L2). No split VALU in loop.
// Outputs STh/STl [b][s][768], Shv [b][o][s].
// -----------------------------------------------------------------------------
__global__ __launch_bounds__(256) void proj_k(const __bf16* __restrict__ cTh,
                                              const __bf16* __restrict__ cTl,
                                              const __bf16* __restrict__ Wh,
                                              const __bf16* __restrict__ Wl,
                                              __bf16* __restrict__ STh,
                                              __bf16* __restrict__ STl,
                                              __bf16* __restrict__ Shv,
                                              int bh) {
  const int bb = blockIdx.y, b = bh * NBH + bb;
  const int o0 = blockIdx.x * 32;
  const int t = threadIdx.x, w = t >> 6, lane = t & 63;
  const int lr = lane & 15, lg = lane >> 4;
  const int ws = w >> 1, wq = w & 1;
  __shared__ __bf16 AhL[128][32];
  __shared__ __bf16 AlL[128][32];

  v4f acc[4];
#pragma unroll
  for (int fr = 0; fr < 4; ++fr) acc[fr] = (v4f){0.f, 0.f, 0.f, 0.f};

  // A stage map (identical to qk_k)
  const int ra = t >> 1, ca0 = (t & 1) * 2;
  const int swA = (ra >> 1) & 3;
  const int pa0 = (ca0 ^ swA) * 8, pa1 = ((ca0 + 1) ^ swA) * 8;
  const __bf16* pAh = cTh + ((size_t)bb * SLN + ra) * IDF;
  const __bf16* pAl = cTl + ((size_t)bb * SLN + ra) * IDF;
  // W frag pointer
  const size_t wOff = (size_t)(o0 + wq * 16 + lr) * IDF + lg * 8;

  uint4 rAh0, rAh1, rAl0, rAl1;
  v8bf bhc, blc;
  rAh0 = *(const uint4*)(pAh + ca0 * 8);
  rAh1 = *(const uint4*)(pAh + ca0 * 8 + 8);
  rAl0 = *(const uint4*)(pAl + ca0 * 8);
  rAl1 = *(const uint4*)(pAl + ca0 * 8 + 8);
  bhc = *(const v8bf*)(Wh + wOff);
  blc = *(const v8bf*)(Wl + wOff);

#pragma unroll 2
  for (int it = 0; it < NT; ++it) {
    __syncthreads();
    *(uint4*)&AhL[ra][pa0] = rAh0;
    *(uint4*)&AhL[ra][pa1] = rAh1;
    *(uint4*)&AlL[ra][pa0] = rAl0;
    *(uint4*)&AlL[ra][pa1] = rAl1;

    uint4 nAh0, nAh1, nAl0, nAl1;
    v8bf bhn, bln;
    if (it + 1 < NT) {
      const int c0n = (it + 1) * 32;
      nAh0 = *(const uint4*)(pAh + c0n + ca0 * 8);
      nAh1 = *(const uint4*)(pAh + c0n + ca0 * 8 + 8);
      nAl0 = *(const uint4*)(pAl + c0n + ca0 * 8);
      nAl1 = *(const uint4*)(pAl + c0n + ca0 * 8 + 8);
      bhn = *(const v8bf*)(Wh + wOff + c0n);
      bln = *(const v8bf*)(Wl + wOff + c0n);
    }
    __syncthreads();

#pragma unroll
    for (int fr = 0; fr < 4; ++fr) {
      const int r = ws * 64 + fr * 16 + lr;
      const int p = (lg ^ ((r >> 1) & 3)) * 8;
      v8bf ah = *(const v8bf*)&AhL[r][p];
      v8bf al = *(const v8bf*)&AlL[r][p];
      acc[fr] = MFMA16(ah, bhc, acc[fr], 0, 0, 0);
      acc[fr] = MFMA16(ah, blc, acc[fr], 0, 0, 0);
      acc[fr] = MFMA16(al, bhc, acc[fr], 0, 0, 0);
    }
    if (it + 1 < NT) {
      rAh0 = nAh0; rAh1 = nAh1; rAl0 = nAl0; rAl1 = nAl1;
      bhc = bhn; blc = bln;
    }
  }

  const int o = o0 + wq * 16 + lr;
#pragma unroll
  for (int fr = 0; fr < 4; ++fr) {
    __bf16 hp[4];
#pragma unroll
    for (int r = 0; r < 4; ++r) {
      int s = ws * 64 + fr * 16 + lg * 4 + r;
      __bf16 h, l;
      split2(acc[fr][r], h, l);
      STh[((size_t)b * SLN + s) * IDF + o] = h;
      STl[((size_t)b * SLN + s) * IDF + o] = l;
      hp[r] = h;
    }
    *(v4bf*)(Shv + ((size_t)b * IDF + o) * SLN + ws * 64 + fr * 16 + lg * 4) =
        (v4bf){hp[0], hp[1], hp[2], hp[3]};
  }
}

// -----------------------------------------------------------------------------
// K2 qk: unchanged from round 5 (2-phase reg-staged pipeline).
// -----------------------------------------------------------------------------
__global__ __launch_bounds__(256) void qk_k(const float* __restrict__ input,
                                            const __bf16* __restrict__ STh,
                                            const __bf16* __restrict__ STl,
                                            const int* __restrict__ mask,
                                            __bf16* __restrict__ Ppv,
                                            float* __restrict__ attn_out) {
  const int b = blockIdx.y, q0 = blockIdx.x * 64;
  const int t = threadIdx.x, w = t >> 6, lane = t & 63;
  const int lr = lane & 15, lg = lane >> 4;
  __shared__ __bf16 AhL[128][32];
  __shared__ __bf16 AlL[128][32];
  __shared__ __align__(16) float tiL[32][66];
  __shared__ float msk[SLN];
  if (t < SLN) msk[t] = -10000.0f * (float)mask[b * SLN + t];

  v4f acc[8];
#pragma unroll
  for (int fr = 0; fr < 8; ++fr) acc[fr] = (v4f){0.f, 0.f, 0.f, 0.f};

  const int ra = t >> 1, ca0 = (t & 1) * 2;
  const int swA = (ra >> 1) & 3;
  const int pa0 = (ca0 ^ swA) * 8, pa1 = ((ca0 + 1) ^ swA) * 8;
  const int rb = t >> 3, cb = (t & 7) * 8;
  const __bf16* pSTh = STh + ((size_t)b * SLN + ra) * IDF;
  const __bf16* pSTl = STl + ((size_t)b * SLN + ra) * IDF;
  const float*  pIn  = input + ((size_t)b * IDF + rb) * QLN + q0 + cb;

  uint4 rAh0, rAh1, rAl0, rAl1;
  float4 rT0, rT1;
  rAh0 = *(const uint4*)(pSTh + ca0 * 8);
  rAh1 = *(const uint4*)(pSTh + ca0 * 8 + 8);
  rAl0 = *(const uint4*)(pSTl + ca0 * 8);
  rAl1 = *(const uint4*)(pSTl + ca0 * 8 + 8);
  rT0 = *(const float4*)(pIn);
  rT1 = *(const float4*)(pIn + 4);

#pragma unroll 2
  for (int it = 0; it < NT; ++it) {
    __syncthreads();
    *(uint4*)&AhL[ra][pa0] = rAh0;
    *(uint4*)&AhL[ra][pa1] = rAh1;
    *(uint4*)&AlL[ra][pa0] = rAl0;
    *(uint4*)&AlL[ra][pa1] = rAl1;
    *(float2*)&tiL[rb][cb]     = make_float2(rT0.x, rT0.y);
    *(float2*)&tiL[rb][cb + 2] = make_float2(rT0.z, rT0.w);
    *(float2*)&tiL[rb][cb + 4] = make_float2(rT1.x, rT1.y);
    *(float2*)&tiL[rb][cb + 6] = make_float2(rT1.z, rT1.w);

    uint4 nAh0, nAh1, nAl0, nAl1;
    float4 nT0, nT1;
    if (it + 1 < NT) {
      const int i0n = (it + 1) * 32;
      nAh0 = *(const uint4*)(pSTh + i0n + ca0 * 8);
      nAh1 = *(const uint4*)(pSTh + i0n + ca0 * 8 + 8);
      nAl0 = *(const uint4*)(pSTl + i0n + ca0 * 8);
      nAl1 = *(const uint4*)(pSTl + i0n + ca0 * 8 + 8);
      nT0 = *(const float4*)(pIn + (size_t)(it + 1) * 32 * QLN);
      nT1 = *(const float4*)(pIn + (size_t)(it + 1) * 32 * QLN + 4);
    }
    __syncthreads();

    v8bf bh, bl;
#pragma unroll
    for (int e = 0; e < 8; ++e) {
      __bf16 h, l;
      split2(tiL[lg * 8 + e][w * 16 + lr], h, l);
      bh[e] = h;
      bl[e] = l;
    }
#pragma unroll
    for (int fr = 0; fr < 8; ++fr) {
      const int r = fr * 16 + lr;
      const int p = (lg ^ ((r >> 1) & 3)) * 8;
      v8bf ah = *(const v8bf*)&AhL[r][p];
      v8bf al = *(const v8bf*)&AlL[r][p];
      acc[fr] = MFMA16(ah, bh, acc[fr], 0, 0, 0);
      acc[fr] = MFMA16(ah, bl, acc[fr], 0, 0, 0);
      acc[fr] = MFMA16(al, bh, acc[fr], 0, 0, 0);
    }
    if (it + 1 < NT) {
      rAh0 = nAh0; rAh1 = nAh1; rAl0 = nAl0; rAl1 = nAl1;
      rT0 = nT0; rT1 = nT1;
    }
  }

  const int q = q0 + w * 16 + lr;
  float mx = -3.0e38f;
#pragma unroll
  for (int fr = 0; fr < 8; ++fr)
#pragma unroll
    for (int r = 0; r < 4; ++r) {
      acc[fr][r] += msk[fr * 16 + lg * 4 + r];
      mx = fmaxf(mx, acc[fr][r]);
    }
  mx = fmaxf(mx, __shfl_xor(mx, 16));
  mx = fmaxf(mx, __shfl_xor(mx, 32));
  float sum = 0.f;
#pragma unroll
  for (int fr = 0; fr < 8; ++fr)
#pragma unroll
    for (int r = 0; r < 4; ++r) {
      float e = __expf(acc[fr][r] - mx);
      acc[fr][r] = e;
      sum += e;
    }
  sum += __shfl_xor(sum, 16);
  sum += __shfl_xor(sum, 32);
  const float inv = 1.0f / sum;
#pragma unroll
  for (int fr = 0; fr < 8; ++fr) {
    __bf16 hp[4];
#pragma unroll
    for (int r = 0; r < 4; ++r) {
      float p = acc[fr][r] * inv;
      attn_out[((size_t)b * SLN + fr * 16 + lg * 4 + r) * QLN + q] = p;
      hp[r] = (__bf16)p;
    }
    *(v4bf*)(Ppv + ((size_t)b * QLN + q) * SLN + fr * 16 + lg * 4) =
        (v4bf){hp[0], hp[1], hp[2], hp[3]};
  }
}

// -----------------------------------------------------------------------------
// K3 pv: unchanged from round 5.
// -----------------------------------------------------------------------------
__global__ __launch_bounds__(256) void pv_k(const __bf16* __restrict__ Shv,
                                            const __bf16* __restrict__ Ppv,
                                            float* __restrict__ wc) {
  const int b = blockIdx.z, i0 = blockIdx.y * 128, q0 = blockIdx.x * 128;
  const int t = threadIdx.x, w = t >> 6, lane = t & 63;
  const int lr = lane & 15, lg = lane >> 4;
  __shared__ __align__(16) __bf16 PL[128][136];
  {
    const int pr = t >> 1, pc = (t & 1) * 64;
    const __bf16* src = Ppv + ((size_t)b * QLN + q0 + pr) * SLN + pc;
#pragma unroll
    for (int j = 0; j < 8; ++j)
      *(uint4*)&PL[pr][pc + j * 8] = *(const uint4*)(src + j * 8);
  }
  __syncthreads();
  v4f acc[2][8];
#pragma unroll
  for (int fr = 0; fr < 2; ++fr)
#pragma unroll
    for (int fc = 0; fc < 8; ++fc) acc[fr][fc] = (v4f){0.f, 0.f, 0.f, 0.f};
#pragma unroll
  for (int kt = 0; kt < 4; ++kt) {
    const int k0 = kt * 32 + lg * 8;
    v8bf a0 = *(const v8bf*)(Shv + ((size_t)b * IDF + i0 + w * 32 + lr) * SLN + k0);
    v8bf a1 = *(const v8bf*)(Shv + ((size_t)b * IDF + i0 + w * 32 + 16 + lr) * SLN + k0);
#pragma unroll
    for (int fc = 0; fc < 8; ++fc) {
      v8bf pb = *(const v8bf*)&PL[fc * 16 + lr][k0];
      acc[0][fc] = MFMA16(a0, pb, acc[0][fc], 0, 0, 0);
      acc[1][fc] = MFMA16(a1, pb, acc[1][fc], 0, 0, 0);
    }
  }
#pragma unroll
  for (int fr = 0; fr < 2; ++fr)
#pragma unroll
    for (int fc = 0; fc < 8; ++fc)
#pragma unroll
      for (int r = 0; r < 4; ++r)
        wc[((size_t)b * IDF + i0 + w * 32 + fr * 16 + lg * 4 + r) * QLN +
           q0 + fc * 16 + lr] = acc[fr][fc][r];
}

// -----------------------------------------------------------------------------
extern "C" void kernel_launch(void* const* d_in, const int* in_sizes, int n_in,
                              void* d_out, int out_size, void* d_ws, size_t ws_size,
                              hipStream_t stream) {
  const float* input   = (const float*)d_in[0];  // [B, IDF, 32, 32]
  const float* context = (const float*)d_in[1];  // [B, CDF, SL]
  const int*   mask    = (const int*)d_in[2];    // [B, SL]
  const float* w_conv  = (const float*)d_in[3];  // [IDF, CDF]

  float* out      = (float*)d_out;
  float* wc       = out;                          // [B, IDF, QL]
  float* attn_out = out + (size_t)NB * IDF * QLN; // [B, SL, QL]

  // ws layout (bf16 elems):
  //   Wh [0,WE), Wl [WE,2WE)                      -- dead after proj
  //   cTh [2WE, 2WE+SEh), cTl [+SEh)              -- half-batch ctxT, reused 2x
  //   STh [2WE+2SEh, +SE), STl, Shv
  // total = 2WE + 2SEh + 3SE = 27,525,120 B (< 29,360,128 proven OK)
  // Ppv aliases [0, 2WE+2SEh) = 4,325,376 elems >= PE (written by qk,
  // after proj completes; stream-serialized).
  __bf16* wsb = (__bf16*)d_ws;
  const size_t WE  = (size_t)IDF * IDF;         // 589,824
  const size_t SEh = (size_t)NBH * SLN * IDF;   // 1,572,864
  const size_t SE  = (size_t)NB * SLN * IDF;    // 3,145,728
  __bf16* Wh  = wsb;
  __bf16* Wl  = Wh + WE;
  __bf16* cTh = wsb + 2 * WE;
  __bf16* cTl = cTh + SEh;
  __bf16* STh = wsb + 2 * WE + 2 * SEh;
  __bf16* STl = STh + SE;
  __bf16* Shv = STl + SE;
  __bf16* Ppv = wsb;

  prep_w<<<576, 256, 0, stream>>>(w_conv, Wh, Wl);
  for (int bh = 0; bh < 2; ++bh) {
    prep_ctx<<<dim3(12, NBH), 256, 0, stream>>>(context, cTh, cTl, bh);
    proj_k<<<dim3(24, NBH), 256, 0, stream>>>(cTh, cTl, Wh, Wl, STh, STl, Shv, bh);
  }
  qk_k<<<dim3(16, NB), 256, 0, stream>>>(input, STh, STl, mask, Ppv, attn_out);
  pv_k<<<dim3(8, 6, NB), 256, 0, stream>>>(Shv, Ppv, wc);
}

// Round 7
// 131.623 us; speedup vs baseline: 1.1284x; 1.1284x over previous
//
#include <hip/hip_runtime.h>

#define NB  32
#define IDF 768
#define SLN 128
#define QLN 1024
#define NT  24   // IDF/32 k-tiles

typedef __bf16 v8bf __attribute__((ext_vector_type(8)));
typedef __bf16 v4bf __attribute__((ext_vector_type(4)));
typedef float  v4f  __attribute__((ext_vector_type(4)));

#define MFMA16 __builtin_amdgcn_mfma_f32_16x16x32_bf16

__device__ __forceinline__ void split2(float x, __bf16& h, __bf16& l) {
  h = (__bf16)x;
  l = (__bf16)(x - (float)h);
}

// -----------------------------------------------------------------------------
// K0 prep: blocks 0..575 split W -> Wh/Wl; blocks 576..959 transpose+split
// ctx [b][c][s] -> cTh/cTl [b][s][c] (full batch).
// -----------------------------------------------------------------------------
__global__ __launch_bounds__(256) void prep_k(const float* __restrict__ W,
                                              const float* __restrict__ ctx,
                                              __bf16* __restrict__ Wh,
                                              __bf16* __restrict__ Wl,
                                              __bf16* __restrict__ cTh,
                                              __bf16* __restrict__ cTl) {
  const int bid = blockIdx.x, t = threadIdx.x;
  __shared__ float tl[64][133];
  if (bid < 576) {
    int idx = bid * 1024 + t * 4;
    float4 v = *(const float4*)(W + idx);
    float vals[4] = {v.x, v.y, v.z, v.w};
    v4bf h, l;
#pragma unroll
    for (int e = 0; e < 4; ++e) {
      __bf16 hh, ll;
      split2(vals[e], hh, ll);
      h[e] = hh;
      l[e] = ll;
    }
    *(v4bf*)(Wh + idx) = h;
    *(v4bf*)(Wl + idx) = l;
    return;
  }
  const int cid = bid - 576;
  const int b = cid / 12, c0 = (cid % 12) * 64;
#pragma unroll
  for (int j = 0; j < 8; ++j) {  // load 64c x 128s, coalesced
    int u = j * 256 + t;
    int c = u >> 5, s4 = (u & 31) * 4;
    *(float4*)&tl[c][s4] =
        *(const float4*)(ctx + ((size_t)b * IDF + c0 + c) * SLN + s4);
  }
  __syncthreads();
#pragma unroll
  for (int j = 0; j < 8; ++j) {  // write [s][c], split
    int u = j * 256 + t;
    int s = u >> 4, c4 = (u & 15) * 4;
    v4bf h, l;
#pragma unroll
    for (int e = 0; e < 4; ++e) {
      __bf16 hh, ll;
      split2(tl[c4 + e][s], hh, ll);
      h[e] = hh;
      l[e] = ll;
    }
    *(v4bf*)(cTh + ((size_t)b * SLN + s) * IDF + c0 + c4) = h;
    *(v4bf*)(cTl + ((size_t)b * SLN + s) * IDF + c0 + c4) = l;
  }
}

// -----------------------------------------------------------------------------
// K1 proj: D[s][o] = sum_c ctxT[s][c] * W[o][c].  Tile 128s x 32o, grid
// (24, 32) = 768 blocks, 4 waves (ws = w>>1 s-half, wq = w&1 o-16).
// A = ctxT hi/lo via chunk-XOR-swizzled LDS; B = Wh/Wl frags reg-prefetched
// from L2. Outputs STh/STl [b][s][768], Shv [b][o][s].
// -----------------------------------------------------------------------------
__global__ __launch_bounds__(256) void proj_k(const __bf16* __restrict__ cTh,
                                              const __bf16* __restrict__ cTl,
                                              const __bf16* __restrict__ Wh,
                                              const __bf16* __restrict__ Wl,
                                              __bf16* __restrict__ STh,
                                              __bf16* __restrict__ STl,
                                              __bf16* __restrict__ Shv) {
  const int b = blockIdx.y, o0 = blockIdx.x * 32;
  const int t = threadIdx.x, w = t >> 6, lane = t & 63;
  const int lr = lane & 15, lg = lane >> 4;
  const int ws = w >> 1, wq = w & 1;
  __shared__ __bf16 AhL[128][32];
  __shared__ __bf16 AlL[128][32];

  v4f acc[4];
#pragma unroll
  for (int fr = 0; fr < 4; ++fr) acc[fr] = (v4f){0.f, 0.f, 0.f, 0.f};

  const int ra = t >> 1, ca0 = (t & 1) * 2;
  const int swA = (ra >> 1) & 3;
  const int pa0 = (ca0 ^ swA) * 8, pa1 = ((ca0 + 1) ^ swA) * 8;
  const __bf16* pAh = cTh + ((size_t)b * SLN + ra) * IDF;
  const __bf16* pAl = cTl + ((size_t)b * SLN + ra) * IDF;
  const size_t wOff = (size_t)(o0 + wq * 16 + lr) * IDF + lg * 8;

  uint4 rAh0, rAh1, rAl0, rAl1;
  v8bf bhc, blc;
  rAh0 = *(const uint4*)(pAh + ca0 * 8);
  rAh1 = *(const uint4*)(pAh + ca0 * 8 + 8);
  rAl0 = *(const uint4*)(pAl + ca0 * 8);
  rAl1 = *(const uint4*)(pAl + ca0 * 8 + 8);
  bhc = *(const v8bf*)(Wh + wOff);
  blc = *(const v8bf*)(Wl + wOff);

#pragma unroll 2
  for (int it = 0; it < NT; ++it) {
    __syncthreads();
    *(uint4*)&AhL[ra][pa0] = rAh0;
    *(uint4*)&AhL[ra][pa1] = rAh1;
    *(uint4*)&AlL[ra][pa0] = rAl0;
    *(uint4*)&AlL[ra][pa1] = rAl1;

    uint4 nAh0, nAh1, nAl0, nAl1;
    v8bf bhn, bln;
    if (it + 1 < NT) {
      const int c0n = (it + 1) * 32;
      nAh0 = *(const uint4*)(pAh + c0n + ca0 * 8);
      nAh1 = *(const uint4*)(pAh + c0n + ca0 * 8 + 8);
      nAl0 = *(const uint4*)(pAl + c0n + ca0 * 8);
      nAl1 = *(const uint4*)(pAl + c0n + ca0 * 8 + 8);
      bhn = *(const v8bf*)(Wh + wOff + c0n);
      bln = *(const v8bf*)(Wl + wOff + c0n);
    }
    __syncthreads();

#pragma unroll
    for (int fr = 0; fr < 4; ++fr) {
      const int r = ws * 64 + fr * 16 + lr;
      const int p = (lg ^ ((r >> 1) & 3)) * 8;
      v8bf ah = *(const v8bf*)&AhL[r][p];
      v8bf al = *(const v8bf*)&AlL[r][p];
      acc[fr] = MFMA16(ah, bhc, acc[fr], 0, 0, 0);
      acc[fr] = MFMA16(ah, blc, acc[fr], 0, 0, 0);
      acc[fr] = MFMA16(al, bhc, acc[fr], 0, 0, 0);
    }
    if (it + 1 < NT) {
      rAh0 = nAh0; rAh1 = nAh1; rAl0 = nAl0; rAl1 = nAl1;
      bhc = bhn; blc = bln;
    }
  }

  const int o = o0 + wq * 16 + lr;
#pragma unroll
  for (int fr = 0; fr < 4; ++fr) {
    __bf16 hp[4];
#pragma unroll
    for (int r = 0; r < 4; ++r) {
      int s = ws * 64 + fr * 16 + lg * 4 + r;
      __bf16 h, l;
      split2(acc[fr][r], h, l);
      STh[((size_t)b * SLN + s) * IDF + o] = h;
      STl[((size_t)b * SLN + s) * IDF + o] = l;
      hp[r] = h;
    }
    *(v4bf*)(Shv + ((size_t)b * IDF + o) * SLN + ws * 64 + fr * 16 + lg * 4) =
        (v4bf){hp[0], hp[1], hp[2], hp[3]};
  }
}

// -----------------------------------------------------------------------------
// K2 qk: 512 threads = 8 waves; wave w: wq = w&3 (q-16), sh = w>>2 (s-half 64).
// Staging: threads 0..255 stage A-hi, 256..511 stage A-lo (round-6-verified
// XOR map); all threads stage input f32 tile. 2-phase reg-prefetch pipeline.
// Cross-wave softmax over the two s-halves via LDS. Writes attn_out + Ppv.
// -----------------------------------------------------------------------------
__global__ __launch_bounds__(512) void qk_k(const float* __restrict__ input,
                                            const __bf16* __restrict__ STh,
                                            const __bf16* __restrict__ STl,
                                            const int* __restrict__ mask,
                                            __bf16* __restrict__ Ppv,
                                            float* __restrict__ attn_out) {
  const int b = blockIdx.y, q0 = blockIdx.x * 64;
  const int t = threadIdx.x, w = t >> 6, lane = t & 63;
  const int lr = lane & 15, lg = lane >> 4;
  const int wq = w & 3, sh = w >> 2;
  __shared__ __bf16 AhL[128][32];
  __shared__ __bf16 AlL[128][32];
  __shared__ __align__(16) float tiL[32][66];
  __shared__ float msk[SLN];
  __shared__ float redm[2][4][16], reds[2][4][16];
  if (t < SLN) msk[t] = -10000.0f * (float)mask[b * SLN + t];

  v4f acc[4];
#pragma unroll
  for (int fr = 0; fr < 4; ++fr) acc[fr] = (v4f){0.f, 0.f, 0.f, 0.f};

  // A-stage: per 256-thread half, ra = u>>1 (row s), two chunk-pairs, XOR swz
  const int u = t & 255;
  const int ra = u >> 1, ca0 = (u & 1) * 2;
  const int swA = (ra >> 1) & 3;
  const int pa0 = (ca0 ^ swA) * 8, pa1 = ((ca0 + 1) ^ swA) * 8;
  const __bf16* pA = ((t < 256) ? STh : STl) + ((size_t)b * SLN + ra) * IDF;
  __bf16* dA = (t < 256) ? &AhL[0][0] : &AlL[0][0];
  __bf16* dA0 = dA + ra * 32 + pa0;
  __bf16* dA1 = dA + ra * 32 + pa1;
  // input stage: rb row, 4 floats
  const int rb = t >> 4, cb = (t & 15) * 4;
  const float* pIn = input + ((size_t)b * IDF + rb) * QLN + q0 + cb;

  uint4 rA0 = *(const uint4*)(pA + ca0 * 8);
  uint4 rA1 = *(const uint4*)(pA + ca0 * 8 + 8);
  float4 rT = *(const float4*)(pIn);

#pragma unroll 2
  for (int it = 0; it < NT; ++it) {
    __syncthreads();
    *(uint4*)dA0 = rA0;
    *(uint4*)dA1 = rA1;
    *(float2*)&tiL[rb][cb]     = make_float2(rT.x, rT.y);
    *(float2*)&tiL[rb][cb + 2] = make_float2(rT.z, rT.w);

    uint4 nA0, nA1;
    float4 nT;
    if (it + 1 < NT) {
      const int i0n = (it + 1) * 32;
      nA0 = *(const uint4*)(pA + i0n + ca0 * 8);
      nA1 = *(const uint4*)(pA + i0n + ca0 * 8 + 8);
      nT = *(const float4*)(pIn + (size_t)(it + 1) * 32 * QLN);
    }
    __syncthreads();

    v8bf bh, bl;
#pragma unroll
    for (int e = 0; e < 8; ++e) {  // 2-way banks (stride 66 words)
      __bf16 h, l;
      split2(tiL[lg * 8 + e][wq * 16 + lr], h, l);
      bh[e] = h;
      bl[e] = l;
    }
#pragma unroll
    for (int fr = 0; fr < 4; ++fr) {
      const int r = sh * 64 + fr * 16 + lr;
      const int p = (lg ^ ((r >> 1) & 3)) * 8;
      v8bf ah = *(const v8bf*)&AhL[r][p];
      v8bf al = *(const v8bf*)&AlL[r][p];
      acc[fr] = MFMA16(ah, bh, acc[fr], 0, 0, 0);
      acc[fr] = MFMA16(ah, bl, acc[fr], 0, 0, 0);
      acc[fr] = MFMA16(al, bh, acc[fr], 0, 0, 0);
    }
    if (it + 1 < NT) {
      rA0 = nA0; rA1 = nA1; rT = nT;
    }
  }

  // softmax over s=128 for q = q0 + wq*16 + lr; wave owns 64 s (half sh)
  const int q = q0 + wq * 16 + lr;
  float mx = -3.0e38f;
#pragma unroll
  for (int fr = 0; fr < 4; ++fr)
#pragma unroll
    for (int r = 0; r < 4; ++r) {
      acc[fr][r] += msk[sh * 64 + fr * 16 + lg * 4 + r];
      mx = fmaxf(mx, acc[fr][r]);
    }
  mx = fmaxf(mx, __shfl_xor(mx, 16));
  mx = fmaxf(mx, __shfl_xor(mx, 32));
  if (lg == 0) redm[sh][wq][lr] = mx;
  __syncthreads();
  mx = fmaxf(redm[0][wq][lr], redm[1][wq][lr]);
  float sum = 0.f;
#pragma unroll
  for (int fr = 0; fr < 4; ++fr)
#pragma unroll
    for (int r = 0; r < 4; ++r) {
      float e = __expf(acc[fr][r] - mx);
      acc[fr][r] = e;
      sum += e;
    }
  sum += __shfl_xor(sum, 16);
  sum += __shfl_xor(sum, 32);
  if (lg == 0) reds[sh][wq][lr] = sum;
  __syncthreads();
  const float inv = 1.0f / (reds[0][wq][lr] + reds[1][wq][lr]);
#pragma unroll
  for (int fr = 0; fr < 4; ++fr) {
    __bf16 hp[4];
#pragma unroll
    for (int r = 0; r < 4; ++r) {
      float p = acc[fr][r] * inv;
      attn_out[((size_t)b * SLN + sh * 64 + fr * 16 + lg * 4 + r) * QLN + q] = p;
      hp[r] = (__bf16)p;
    }
    *(v4bf*)(Ppv + ((size_t)b * QLN + q) * SLN + sh * 64 + fr * 16 + lg * 4) =
        (v4bf){hp[0], hp[1], hp[2], hp[3]};
  }
}

// -----------------------------------------------------------------------------
// K3 pv: wc[i][q] = sum_s Shv[i][s] * P[q][s].  Grid (8,6,32) = 1536 blocks.
// P tile in LDS; Shv fragments direct from L2; no barriers in MFMA loop.
// -----------------------------------------------------------------------------
__global__ __launch_bounds__(256) void pv_k(const __bf16* __restrict__ Shv,
                                            const __bf16* __restrict__ Ppv,
                                            float* __restrict__ wc) {
  const int b = blockIdx.z, i0 = blockIdx.y * 128, q0 = blockIdx.x * 128;
  const int t = threadIdx.x, w = t >> 6, lane = t & 63;
  const int lr = lane & 15, lg = lane >> 4;
  __shared__ __align__(16) __bf16 PL[128][136];
  {
    const int pr = t >> 1, pc = (t & 1) * 64;
    const __bf16* src = Ppv + ((size_t)b * QLN + q0 + pr) * SLN + pc;
#pragma unroll
    for (int j = 0; j < 8; ++j)
      *(uint4*)&PL[pr][pc + j * 8] = *(const uint4*)(src + j * 8);
  }
  __syncthreads();
  v4f acc[2][8];
#pragma unroll
  for (int fr = 0; fr < 2; ++fr)
#pragma unroll
    for (int fc = 0; fc < 8; ++fc) acc[fr][fc] = (v4f){0.f, 0.f, 0.f, 0.f};
#pragma unroll
  for (int kt = 0; kt < 4; ++kt) {
    const int k0 = kt * 32 + lg * 8;
    v8bf a0 = *(const v8bf*)(Shv + ((size_t)b * IDF + i0 + w * 32 + lr) * SLN + k0);
    v8bf a1 = *(const v8bf*)(Shv + ((size_t)b * IDF + i0 + w * 32 + 16 + lr) * SLN + k0);
#pragma unroll
    for (int fc = 0; fc < 8; ++fc) {
      v8bf pb = *(const v8bf*)&PL[fc * 16 + lr][k0];
      acc[0][fc] = MFMA16(a0, pb, acc[0][fc], 0, 0, 0);
      acc[1][fc] = MFMA16(a1, pb, acc[1][fc], 0, 0, 0);
    }
  }
#pragma unroll
  for (int fr = 0; fr < 2; ++fr)
#pragma unroll
    for (int fc = 0; fc < 8; ++fc)
#pragma unroll
      for (int r = 0; r < 4; ++r)
        wc[((size_t)b * IDF + i0 + w * 32 + fr * 16 + lg * 4 + r) * QLN +
           q0 + fc * 16 + lr] = acc[fr][fc][r];
}

// -----------------------------------------------------------------------------
extern "C" void kernel_launch(void* const* d_in, const int* in_sizes, int n_in,
                              void* d_out, int out_size, void* d_ws, size_t ws_size,
                              hipStream_t stream) {
  const float* input   = (const float*)d_in[0];  // [B, IDF, 32, 32]
  const float* context = (const float*)d_in[1];  // [B, CDF, SL]
  const int*   mask    = (const int*)d_in[2];    // [B, SL]
  const float* w_conv  = (const float*)d_in[3];  // [IDF, CDF]

  float* out      = (float*)d_out;
  float* wc       = out;                          // [B, IDF, QL]
  float* attn_out = out + (size_t)NB * IDF * QLN; // [B, SL, QL]

  // Scratch plan:
  //  - wc output region (100.66 MB, written only by pv at the END) doubles as
  //    scratch for cTh|cTl|Wh|Wl (14.9 MB), all dead before pv runs.
  //  - d_ws: Ppv | STh | STl | Shv = 13,631,488 bf16 = 27,262,976 B
  //    (< 29,360,128 B proven available).
  const size_t SE = (size_t)NB * SLN * IDF;  // 3,145,728
  const size_t WE = (size_t)IDF * IDF;       // 589,824
  const size_t PE = (size_t)NB * QLN * SLN;  // 4,194,304
  __bf16* wsb = (__bf16*)d_ws;
  __bf16* Ppv = wsb;
  __bf16* STh = wsb + PE;
  __bf16* STl = STh + SE;
  __bf16* Shv = STl + SE;
  __bf16* scr = (__bf16*)wc;  // scratch in output region
  __bf16* cTh = scr;
  __bf16* cTl = cTh + SE;
  __bf16* Wh  = cTl + SE;
  __bf16* Wl  = Wh + WE;

  prep_k<<<960, 256, 0, stream>>>(w_conv, context, Wh, Wl, cTh, cTl);
  proj_k<<<dim3(24, NB), 256, 0, stream>>>(cTh, cTl, Wh, Wl, STh, STl, Shv);
  qk_k<<<dim3(16, NB), 512, 0, stream>>>(input, STh, STl, mask, Ppv, attn_out);
  pv_k<<<dim3(8, 6, NB), 256, 0, stream>>>(Shv, Ppv, wc);
}